// Round 5
// baseline (475.287 us; speedup 1.0000x reference)
//
#include <hip/hip_runtime.h>
#include <hip/hip_bf16.h>

// Problem constants
#define B_   4
#define N_   160
#define D_   64
#define ZI_  64
#define H1_  128
#define H2_  64
#define L_   4
#define LE_  8

// R14 instrumentation: repeat stage_b's whole body this many times so the
// dispatch outranks the 40us workspace fills and exposes its PMCs.
#define REPEAT_ 16

typedef __bf16 bf16x8 __attribute__((ext_vector_type(8)));
typedef float  f32x4  __attribute__((ext_vector_type(4)));
typedef unsigned int u32x4 __attribute__((ext_vector_type(4)));

static __device__ __forceinline__ unsigned pk_bf16(float a, float b) {
    __hip_bfloat162 h = __float22bfloat162_rn(float2{a, b});
    union { __hip_bfloat162 h; unsigned u; } c;
    c.h = h;
    return c.u;
}

// ---------------------------------------------------------------------------
// Stage A: per-(b,i) precompute (scalar). Unchanged from R12.
//   ui[b,i,h]   = ne[b,i]@Wi1[:64] + z_intra[b]@Wi1[128:192] + bi1      (fp32)
//   uq[b,l,i,h] = ne[b,i]@Wl1[:64] + z_inter[b]@Wl1[128:192] + lag[l]@Wl1_l + bl1
//   u rows stored PRE-PERMUTED within each 8-chunk (evens then odds).
//   vpi/vpl = bf16 j-panels, PRE-SWIZZLED (elem h -> granule (h>>3)^(i&7)).
// Blocks 0/1 pack the per-branch setup BLOB (global):
//   [ W2 bf16 fragment-ordered 16384 B | b2 fp32 512 B | w3 fp32 512 B |
//     b3 fp32 4 B | pad -> 20480 B ]
// ---------------------------------------------------------------------------
__global__ __launch_bounds__(128) void stage_a(
    const float* __restrict__ ne,
    const float* __restrict__ zi,
    const float* __restrict__ ze,
    const float* __restrict__ lag,
    const float* __restrict__ Wi1,
    const float* __restrict__ bi1,
    const float* __restrict__ Wl1,
    const float* __restrict__ bl1,
    const float* __restrict__ Wi2,
    const float* __restrict__ bi2,
    const float* __restrict__ Wi3,
    const float* __restrict__ bi3,
    const float* __restrict__ Wl2,
    const float* __restrict__ bl2,
    const float* __restrict__ Wl3,
    const float* __restrict__ bl3,
    float* __restrict__ ui, float* __restrict__ uq,
    __bf16* __restrict__ vpi, __bf16* __restrict__ vpl,
    char* __restrict__ blob_i, char* __restrict__ blob_l)
{
    const int bi = blockIdx.x;       // b*N + i
    const int b  = bi / N_;
    const int h  = threadIdx.x;      // 0..127

    const float* nerow = ne + bi * D_;

    float pi_ = 0.f, pj_ = 0.f, qi_ = 0.f, qj_ = 0.f;
#pragma unroll 16
    for (int d = 0; d < D_; ++d) {
        const float a = nerow[d];
        pi_ += a * Wi1[d * H1_ + h];
        pj_ += a * Wi1[(D_ + d) * H1_ + h];
        qi_ += a * Wl1[d * H1_ + h];
        qj_ += a * Wl1[(D_ + d) * H1_ + h];
    }
    float pz = 0.f, qz = 0.f;
#pragma unroll 16
    for (int z = 0; z < ZI_; ++z) {
        pz += zi[b * ZI_ + z] * Wi1[(2 * D_ + z) * H1_ + h];
        qz += ze[b * ZI_ + z] * Wl1[(2 * D_ + z) * H1_ + h];
    }

    // Even/odd permuted store index (see header).
    const int r7 = h & 7;
    const int hp = (h & ~7) | ((r7 & 1) ? (4 + (r7 >> 1)) : (r7 >> 1));

    ui[bi * H1_ + hp] = pi_ + pz + bi1[h];

    // Pre-swizzled panel store (row&7 == bi&7 since N is a multiple of 8).
    const int hsw = (((h >> 3) ^ (bi & 7)) << 3) | (h & 7);
    vpi[bi * H1_ + hsw] = (__bf16)pj_;
    vpl[bi * H1_ + hsw] = (__bf16)qj_;

    const float qbase = qi_ + qz + bl1[h];
#pragma unroll
    for (int l = 0; l < L_; ++l) {
        float ql = 0.f;
#pragma unroll
        for (int e = 0; e < LE_; ++e)
            ql += lag[l * LE_ + e] * Wl1[(2 * D_ + ZI_ + e) * H1_ + h];
        uq[((b * L_ + l) * N_ + (bi % N_)) * H1_ + hp] = qbase + ql;
    }

    // Pack the setup blob for stage_b.
    if (bi < 2) {
        const float* Wsrc = (bi == 0) ? Wi2 : Wl2;
        char* blob = (bi == 0) ? blob_i : blob_l;
        __bf16* Wdst = (__bf16*)blob;
        // W2 -> bf16 fragment layout: chunk fc = (kt*4+ct)*64 + lane holds
        // the 8 values lane needs for fragment (kt,ct).
#pragma unroll
        for (int r = 0; r < 8; ++r) {
            const int fc = h + 128 * r;
            const int kt = fc >> 8, ct = (fc >> 6) & 3;
            const int q = (fc >> 4) & 3, c = fc & 15;
            bf16x8 t;
#pragma unroll
            for (int j = 0; j < 8; ++j)
                t[j] = (__bf16)Wsrc[(32 * kt + 8 * q + j) * H2_ + 16 * ct + c];
            *(bf16x8*)(Wdst + fc * 8) = t;
        }
        // Biases + w3 (fp32) appended.
        float* bdst = (float*)(blob + 16384);
        const float* b2s = (bi == 0) ? bi2 : bl2;
        const float* w3s = (bi == 0) ? Wi3 : Wl3;
        const float* b3s = (bi == 0) ? bi3 : bl3;
        if (h < H2_) bdst[h] = b2s[h];
        if (h < H2_) bdst[128 + h] = w3s[h];
        if (h == 0)  bdst[256] = b3s[0];
    }
}

// ---------------------------------------------------------------------------
// Stage B (R14 = R12 body x REPEAT_): full-row waves, 800 blocks x 256 thr.
// The ENTIRE body (DMA burst -> drain -> setup -> jt loop -> stores) runs
// REPEAT_ times, idempotently. Purpose: a ~26us-exec kernel becomes ~420us,
// outranking the 40us fills in rocprof top-5 so we finally see VALUBusy /
// MfmaUtil / FETCH_SIZE / VGPR_Count / Occupancy for stage_b itself.
// LDS 43008 B: [panel 40960 = full 160x128 bf16, pre-swizzled][u 2048].
// MFMA 16x16x32 layouts (HW-verified):
//   A: lane holds A[m=lane&15][k=8*(lane>>4)+j]
//   B: lane holds B[k=8*(lane>>4)+j][n=lane&15]
//   C/D: lane holds D[row=4*(lane>>4)+reg][col=lane&15]
// ---------------------------------------------------------------------------
__global__ __launch_bounds__(256, 3) void stage_b(
    const float* __restrict__ ui, const float* __restrict__ uq,
    const __bf16* __restrict__ vpi, const __bf16* __restrict__ vpl,
    const char* __restrict__ blob_i, const char* __restrict__ blob_l,
    float* __restrict__ out)
{
    __shared__ __align__(16) char lds[43008];

    const int t    = threadIdx.x;
    const int wid  = t >> 6;         // 0..3 (row within quad)
    const int lane = t & 63;
    const int q = lane >> 4;
    const int c = lane & 15;

    const int blk  = blockIdx.x;     // 0..799
    const int row0 = blk * 4;        // first row of quad
    const int wave = row0 + wid;     // row id 0..3199

    // Block-uniform sources.
    const __bf16* psrc;
    const char*   bsrc;
    const float*  usrc;
    if (blk < 160) {                 // intra (rows 0..639)
        psrc = vpi + (blk / 40) * (N_ * H1_);
        bsrc = blob_i;
        usrc = ui + row0 * H1_;
    } else {                         // inter (rows 640..3199)
        psrc = vpl + ((blk - 160) / 160) * (N_ * H1_);
        bsrc = blob_l;
        usrc = uq + (row0 - B_ * N_) * H1_;
    }

    const int  i     = (wave < B_ * N_ ? wave : wave - B_ * N_) % N_;
    const long obase = (long)wave * N_;   // holds for both branches

    for (int rep = 0; rep < REPEAT_; ++rep) {

    // 1) DMA burst: 42 KiB in 1 KiB granules over 4 waves (panel 0..39, u 40..41).
    for (int g = wid; g < 42; g += 4) {
        const char* src = (g < 40) ? (const char*)psrc + (g << 10)
                                   : (const char*)usrc + ((g - 40) << 10);
        __builtin_amdgcn_global_load_lds(
            (const __attribute__((address_space(1))) void*)(src + lane * 16),
            (__attribute__((address_space(3))) void*)(lds + (g << 10)),
            16, 0, 0);
    }

    // 2) W2 fragments + biases straight from global blob (L2-hot, one time).
    bf16x8 bfr[4][4];
#pragma unroll
    for (int kt = 0; kt < 4; ++kt)
#pragma unroll
        for (int ct = 0; ct < 4; ++ct)
            bfr[kt][ct] = *(const bf16x8*)(bsrc + ((kt * 4 + ct) * 64 + lane) * 16);

    const float* bf32 = (const float*)(bsrc + 16384);
    float b2c[4], w3c[4];
#pragma unroll
    for (int ct = 0; ct < 4; ++ct) {
        b2c[ct] = bf32[16 * ct + c];
        w3c[ct] = bf32[128 + 16 * ct + c];
    }
    const float b3f = bf32[256];

    __syncthreads();   // drains DMA (vmcnt) for all waves

    // 3) u halves once from LDS (permuted rows: evens at +0..3, odds +4..7).
    const float* ubase = (const float*)(lds + 40960) + wid * H1_;
    f32x4 ue[4], uo[4];
#pragma unroll
    for (int kt = 0; kt < 4; ++kt) {
        ue[kt] = *(const f32x4*)(ubase + 32 * kt + 8 * q);
        uo[kt] = *(const f32x4*)(ubase + 32 * kt + 8 * q + 4);
    }

    const __bf16* panel = (const __bf16*)lds;

    // 4) Full-row tile loop: 10 j-tiles.
    for (int jt = 0; jt < 10; ++jt) {
        const __bf16* prow = panel + (16 * jt + c) * H1_;
        f32x4 acc[4];
#pragma unroll
        for (int ct = 0; ct < 4; ++ct)
            acc[ct] = (f32x4){b2c[ct], b2c[ct], b2c[ct], b2c[ct]};

#pragma unroll
        for (int kt = 0; kt < 4; ++kt) {
            const u32x4 vw = *(const u32x4*)(prow + (((4 * kt + q) ^ (c & 7)) << 3));
            union { bf16x8 v; unsigned d[4]; } a;
#pragma unroll
            for (int d = 0; d < 4; ++d) {
                const unsigned w = vw[d];
                const float lo = __uint_as_float(w << 16) + ue[kt][d];
                const float hi = __uint_as_float(w & 0xffff0000u) + uo[kt][d];
                a.d[d] = pk_bf16(fmaxf(lo, 0.f), fmaxf(hi, 0.f));
            }
#pragma unroll
            for (int ct = 0; ct < 4; ++ct)
                acc[ct] = __builtin_amdgcn_mfma_f32_16x16x32_bf16(
                    a.v, bfr[kt][ct], acc[ct], 0, 0, 0);
        }

        // Epilogue: logit[r] = b3 + sum_col relu(H2pre) * w3 (b2 in acc).
        float logit[4];
#pragma unroll
        for (int r = 0; r < 4; ++r) {
            float p = 0.f;
#pragma unroll
            for (int ct = 0; ct < 4; ++ct)
                p += fmaxf(acc[ct][r], 0.f) * w3c[ct];
            p += __shfl_xor(p, 1);
            p += __shfl_xor(p, 2);
            p += __shfl_xor(p, 4);
            p += __shfl_xor(p, 8);
            logit[r] = p;
        }

        if (c < 4) {
            const int j = 16 * jt + 4 * q + c;
            const float lg = logit[c] + b3f;
            const float s = (j == i) ? 0.f : 1.f / (1.f + __expf(-lg));
            out[obase + j] = s;
        }
    }

    __syncthreads();   // keep next rep's DMA from racing this rep's reads

    }  // rep
}

// ---------------------------------------------------------------------------
extern "C" void kernel_launch(void* const* d_in, const int* in_sizes, int n_in,
                              void* d_out, int out_size, void* d_ws, size_t ws_size,
                              hipStream_t stream) {
    const float* ne  = (const float*)d_in[0];
    const float* zi  = (const float*)d_in[1];
    const float* ze  = (const float*)d_in[2];
    const float* lag = (const float*)d_in[3];
    const float* Wi1 = (const float*)d_in[4];
    const float* bi1 = (const float*)d_in[5];
    const float* Wi2 = (const float*)d_in[6];
    const float* bi2 = (const float*)d_in[7];
    const float* Wi3 = (const float*)d_in[8];
    const float* bi3 = (const float*)d_in[9];
    const float* Wl1 = (const float*)d_in[10];
    const float* bl1 = (const float*)d_in[11];
    const float* Wl2 = (const float*)d_in[12];
    const float* bl2 = (const float*)d_in[13];
    const float* Wl3 = (const float*)d_in[14];
    const float* bl3 = (const float*)d_in[15];

    float*  ws     = (float*)d_ws;
    float*  ui     = ws;                        // 640*128 fp32 (permuted rows)
    float*  uqw    = ws + 81920;                // 2560*128 fp32 (permuted rows)
    __bf16* vpi    = (__bf16*)(ws + 409600);    // 640*128 bf16 (pre-swizzled)
    __bf16* vpl    = vpi + 81920;               // 640*128 bf16 (pre-swizzled)
    char*   blob_i = (char*)d_ws + 1966080;     // 20480 B setup blob (intra)
    char*   blob_l = blob_i + 20480;            // 20480 B setup blob (inter)

    stage_a<<<B_ * N_, 128, 0, stream>>>(ne, zi, ze, lag, Wi1, bi1, Wl1, bl1,
                                         Wi2, bi2, Wi3, bi3, Wl2, bl2, Wl3, bl3,
                                         ui, uqw, vpi, vpl, blob_i, blob_l);

    stage_b<<<800, 256, 0, stream>>>(
        ui, uqw, vpi, vpl, blob_i, blob_l,
        (float*)d_out);
}

// Round 6
// 234.921 us; speedup vs baseline: 2.0232x; 2.0232x over previous
//
#include <hip/hip_runtime.h>
#include <hip/hip_bf16.h>

// Problem constants
#define B_   4
#define N_   160
#define D_   64
#define ZI_  64
#define H1_  128
#define H2_  64
#define L_   4
#define LE_  8

typedef __bf16 bf16x8 __attribute__((ext_vector_type(8)));
typedef float  f32x4  __attribute__((ext_vector_type(4)));
typedef unsigned int u32x4 __attribute__((ext_vector_type(4)));

// ---------------------------------------------------------------------------
// Stage A: per-(b,i) precompute (scalar; ~3 µs). Unchanged.
//   ui[b,i,h]   = ne[b,i]@Wi1[:64] + z_intra[b]@Wi1[128:192] + bi1      (fp32)
//   uq[b,l,i,h] = ne[b,i]@Wl1[:64] + z_inter[b]@Wl1[128:192] + lag[l]@Wl1_l + bl1
//   u rows stored PRE-PERMUTED within each 8-chunk (evens then odds) so
//   stage_b fetches MFMA-A even/odd halves as two straight ds_read_b128.
//   vpi/vpl = bf16 j-panels, PRE-SWIZZLED (elem h -> granule (h>>3)^(i&7)).
// Blocks 0/1 pack the per-branch setup BLOB (global, L2-hot for stage_b):
//   [ W2 bf16 fragment-ordered 16384 B | b2 fp32 512 B | w3 fp32 512 B |
//     b3 fp32 4 B | pad -> 20480 B ]
// ---------------------------------------------------------------------------
__global__ __launch_bounds__(128) void stage_a(
    const float* __restrict__ ne,
    const float* __restrict__ zi,
    const float* __restrict__ ze,
    const float* __restrict__ lag,
    const float* __restrict__ Wi1,
    const float* __restrict__ bi1,
    const float* __restrict__ Wl1,
    const float* __restrict__ bl1,
    const float* __restrict__ Wi2,
    const float* __restrict__ bi2,
    const float* __restrict__ Wi3,
    const float* __restrict__ bi3,
    const float* __restrict__ Wl2,
    const float* __restrict__ bl2,
    const float* __restrict__ Wl3,
    const float* __restrict__ bl3,
    float* __restrict__ ui, float* __restrict__ uq,
    __bf16* __restrict__ vpi, __bf16* __restrict__ vpl,
    char* __restrict__ blob_i, char* __restrict__ blob_l)
{
    const int bi = blockIdx.x;       // b*N + i
    const int b  = bi / N_;
    const int h  = threadIdx.x;      // 0..127

    const float* nerow = ne + bi * D_;

    float pi_ = 0.f, pj_ = 0.f, qi_ = 0.f, qj_ = 0.f;
#pragma unroll 16
    for (int d = 0; d < D_; ++d) {
        const float a = nerow[d];
        pi_ += a * Wi1[d * H1_ + h];
        pj_ += a * Wi1[(D_ + d) * H1_ + h];
        qi_ += a * Wl1[d * H1_ + h];
        qj_ += a * Wl1[(D_ + d) * H1_ + h];
    }
    float pz = 0.f, qz = 0.f;
#pragma unroll 16
    for (int z = 0; z < ZI_; ++z) {
        pz += zi[b * ZI_ + z] * Wi1[(2 * D_ + z) * H1_ + h];
        qz += ze[b * ZI_ + z] * Wl1[(2 * D_ + z) * H1_ + h];
    }

    // Even/odd permuted store index (see header).
    const int r7 = h & 7;
    const int hp = (h & ~7) | ((r7 & 1) ? (4 + (r7 >> 1)) : (r7 >> 1));

    ui[bi * H1_ + hp] = pi_ + pz + bi1[h];

    // Pre-swizzled panel store (row&7 == bi&7 since N is a multiple of 8).
    const int hsw = (((h >> 3) ^ (bi & 7)) << 3) | (h & 7);
    vpi[bi * H1_ + hsw] = (__bf16)pj_;
    vpl[bi * H1_ + hsw] = (__bf16)qj_;

    const float qbase = qi_ + qz + bl1[h];
#pragma unroll
    for (int l = 0; l < L_; ++l) {
        float ql = 0.f;
#pragma unroll
        for (int e = 0; e < LE_; ++e)
            ql += lag[l * LE_ + e] * Wl1[(2 * D_ + ZI_ + e) * H1_ + h];
        uq[((b * L_ + l) * N_ + (bi % N_)) * H1_ + hp] = qbase + ql;
    }

    // Pack the setup blob for stage_b.
    if (bi < 2) {
        const float* Wsrc = (bi == 0) ? Wi2 : Wl2;
        char* blob = (bi == 0) ? blob_i : blob_l;
        __bf16* Wdst = (__bf16*)blob;
        // W2 -> bf16 fragment layout: chunk fc = (kt*4+ct)*64 + lane holds
        // the 8 values lane needs for fragment (kt,ct).
#pragma unroll
        for (int r = 0; r < 8; ++r) {
            const int fc = h + 128 * r;
            const int kt = fc >> 8, ct = (fc >> 6) & 3;
            const int q = (fc >> 4) & 3, c = fc & 15;
            bf16x8 t;
#pragma unroll
            for (int j = 0; j < 8; ++j)
                t[j] = (__bf16)Wsrc[(32 * kt + 8 * q + j) * H2_ + 16 * ct + c];
            *(bf16x8*)(Wdst + fc * 8) = t;
        }
        // Biases + w3 (fp32) appended.
        float* bdst = (float*)(blob + 16384);
        const float* b2s = (bi == 0) ? bi2 : bl2;
        const float* w3s = (bi == 0) ? Wi3 : Wl3;
        const float* b3s = (bi == 0) ? bi3 : bl3;
        if (h < H2_) bdst[h] = b2s[h];
        if (h < H2_) bdst[128 + h] = w3s[h];
        if (h == 0)  bdst[256] = b3s[0];
    }
}

// ---------------------------------------------------------------------------
// Stage B (R15): R11's occupancy grid + R12's register-resident setup.
// R14 PMCs showed: VALUBusy 53.5%, MfmaUtil 12.9%, HBM ~0, VGPR 84,
// Occupancy ~3 waves/SIMD -> VALU-issue-bound with ~46% dependency stall.
// Fix both terms:
//  (a) 800 blocks x 512 thr (8 rows x j-half); LDS = half-panel 20480 B +
//      u 4096 B = 24576 B. VGPR 84 <= 85 = __launch_bounds__(512,6) budget
//      -> 3 blocks/CU x 8 waves = 24 waves/CU (6/SIMD, 2x R14). DS traffic
//      stays at R12's low level (1 panel b128/kt; bfr/u register-resident),
//      unlike R11 whose LDS re-reads tripled DS and erased the gain.
//  (b) bf16 pack via plain (__bf16) casts -> compiler emits
//      v_cvt_pk_bf16_f32 (single VALU/pair) instead of
//      __float22bfloat162_rn's software-RNE sequence.
// MFMA 16x16x32 layouts (HW-verified):
//   A: lane holds A[m=lane&15][k=8*(lane>>4)+j]
//   B: lane holds B[k=8*(lane>>4)+j][n=lane&15]
//   C/D: lane holds D[row=4*(lane>>4)+reg][col=lane&15]
// ---------------------------------------------------------------------------
__global__ __launch_bounds__(512, 6) void stage_b(
    const float* __restrict__ ui, const float* __restrict__ uq,
    const __bf16* __restrict__ vpi, const __bf16* __restrict__ vpl,
    const char* __restrict__ blob_i, const char* __restrict__ blob_l,
    float* __restrict__ out)
{
    __shared__ __align__(16) char lds[24576];

    const int t    = threadIdx.x;
    const int wid  = t >> 6;         // 0..7 (row within group)
    const int lane = t & 63;
    const int q = lane >> 4;
    const int c = lane & 15;

    const int blk    = blockIdx.x;   // 0..799
    const int rowgrp = blk >> 1;     // 0..399 (8 rows each)
    const int half   = blk & 1;      // j-half (80 j each)
    const int row0   = rowgrp * 8;   // block-uniform first row
    const int wave   = row0 + wid;   // row id 0..3199

    // Block-uniform sources.
    const __bf16* psrc;
    const char*   bsrc;
    const float*  usrc;
    if (rowgrp < 80) {               // intra (rows 0..639; 20 rowgrps per b)
        psrc = vpi + (rowgrp / 20) * (N_ * H1_);
        bsrc = blob_i;
        usrc = ui + row0 * H1_;
    } else {                         // inter (rows 640..3199; 80 rowgrps per b)
        psrc = vpl + ((rowgrp - 80) / 80) * (N_ * H1_);
        bsrc = blob_l;
        usrc = uq + (row0 - B_ * N_) * H1_;
    }
    psrc += 80 * half * H1_;

    // 1) DMA burst: 24 KiB in 1 KiB granules over 8 waves (panel 0..19, u 20..23).
    //    Dest is wave-uniform base (HW adds lane*16); source carries lane offset.
    for (int g = wid; g < 24; g += 8) {
        const char* src = (g < 20) ? (const char*)psrc + (g << 10)
                                   : (const char*)usrc + ((g - 20) << 10);
        __builtin_amdgcn_global_load_lds(
            (const __attribute__((address_space(1))) void*)(src + lane * 16),
            (__attribute__((address_space(3))) void*)(lds + (g << 10)),
            16, 0, 0);
    }

    // 2) W2 fragments + biases straight from global blob (L2-hot, once per
    //    wave; overlaps the DMA drain).
    bf16x8 bfr[4][4];
#pragma unroll
    for (int kt = 0; kt < 4; ++kt)
#pragma unroll
        for (int ct = 0; ct < 4; ++ct)
            bfr[kt][ct] = *(const bf16x8*)(bsrc + ((kt * 4 + ct) * 64 + lane) * 16);

    const float* bf32 = (const float*)(bsrc + 16384);
    float b2c[4], w3c[4];
#pragma unroll
    for (int ct = 0; ct < 4; ++ct) {
        b2c[ct] = bf32[16 * ct + c];
        w3c[ct] = bf32[128 + 16 * ct + c];
    }
    const float b3f = bf32[256];

    const int  i     = (wave < B_ * N_ ? wave : wave - B_ * N_) % N_;
    const long obase = (long)wave * N_;   // holds for both branches

    __syncthreads();   // drains DMA (vmcnt) for all waves

    // 3) u halves once from LDS (permuted rows: evens at +0..3, odds +4..7).
    const float* ubase = (const float*)(lds + 20480) + wid * H1_;
    f32x4 ue[4], uo[4];
#pragma unroll
    for (int kt = 0; kt < 4; ++kt) {
        ue[kt] = *(const f32x4*)(ubase + 32 * kt + 8 * q);
        uo[kt] = *(const f32x4*)(ubase + 32 * kt + 8 * q + 4);
    }

    const __bf16* panel = (const __bf16*)lds;

    // 4) Half-row tile loop: 5 j-tiles.
    for (int jt = 0; jt < 5; ++jt) {
        const __bf16* prow = panel + (16 * jt + c) * H1_;
        f32x4 acc[4];
#pragma unroll
        for (int ct = 0; ct < 4; ++ct)
            acc[ct] = (f32x4){b2c[ct], b2c[ct], b2c[ct], b2c[ct]};

#pragma unroll
        for (int kt = 0; kt < 4; ++kt) {
            const u32x4 vw = *(const u32x4*)(prow + (((4 * kt + q) ^ (c & 7)) << 3));
            bf16x8 av;
#pragma unroll
            for (int d = 0; d < 4; ++d) {
                const unsigned w = vw[d];
                const float lo = __uint_as_float(w << 16) + ue[kt][d];
                const float hi = __uint_as_float(w & 0xffff0000u) + uo[kt][d];
                av[2 * d]     = (__bf16)fmaxf(lo, 0.f);   // pairs -> v_cvt_pk_bf16_f32
                av[2 * d + 1] = (__bf16)fmaxf(hi, 0.f);
            }
#pragma unroll
            for (int ct = 0; ct < 4; ++ct)
                acc[ct] = __builtin_amdgcn_mfma_f32_16x16x32_bf16(
                    av, bfr[kt][ct], acc[ct], 0, 0, 0);
        }

        // Epilogue: logit[r] = b3 + sum_col relu(H2pre) * w3 (b2 in acc).
        float logit[4];
#pragma unroll
        for (int r = 0; r < 4; ++r) {
            float p = 0.f;
#pragma unroll
            for (int ct = 0; ct < 4; ++ct)
                p += fmaxf(acc[ct][r], 0.f) * w3c[ct];
            p += __shfl_xor(p, 1);
            p += __shfl_xor(p, 2);
            p += __shfl_xor(p, 4);
            p += __shfl_xor(p, 8);
            logit[r] = p;
        }

        if (c < 4) {
            const int j = 80 * half + 16 * jt + 4 * q + c;
            const float lg = logit[c] + b3f;
            const float s = (j == i) ? 0.f : 1.f / (1.f + __expf(-lg));
            out[obase + j] = s;
        }
    }
}

// ---------------------------------------------------------------------------
extern "C" void kernel_launch(void* const* d_in, const int* in_sizes, int n_in,
                              void* d_out, int out_size, void* d_ws, size_t ws_size,
                              hipStream_t stream) {
    const float* ne  = (const float*)d_in[0];
    const float* zi  = (const float*)d_in[1];
    const float* ze  = (const float*)d_in[2];
    const float* lag = (const float*)d_in[3];
    const float* Wi1 = (const float*)d_in[4];
    const float* bi1 = (const float*)d_in[5];
    const float* Wi2 = (const float*)d_in[6];
    const float* bi2 = (const float*)d_in[7];
    const float* Wi3 = (const float*)d_in[8];
    const float* bi3 = (const float*)d_in[9];
    const float* Wl1 = (const float*)d_in[10];
    const float* bl1 = (const float*)d_in[11];
    const float* Wl2 = (const float*)d_in[12];
    const float* bl2 = (const float*)d_in[13];
    const float* Wl3 = (const float*)d_in[14];
    const float* bl3 = (const float*)d_in[15];

    float*  ws     = (float*)d_ws;
    float*  ui     = ws;                        // 640*128 fp32 (permuted rows)
    float*  uqw    = ws + 81920;                // 2560*128 fp32 (permuted rows)
    __bf16* vpi    = (__bf16*)(ws + 409600);    // 640*128 bf16 (pre-swizzled)
    __bf16* vpl    = vpi + 81920;               // 640*128 bf16 (pre-swizzled)
    char*   blob_i = (char*)d_ws + 1966080;     // 20480 B setup blob (intra)
    char*   blob_l = blob_i + 20480;            // 20480 B setup blob (inter)

    stage_a<<<B_ * N_, 128, 0, stream>>>(ne, zi, ze, lag, Wi1, bi1, Wl1, bl1,
                                         Wi2, bi2, Wi3, bi3, Wl2, bl2, Wl3, bl3,
                                         ui, uqw, vpi, vpl, blob_i, blob_l);

    stage_b<<<800, 512, 0, stream>>>(
        ui, uqw, vpi, vpl, blob_i, blob_l,
        (float*)d_out);
}

// Round 7
// 139.224 us; speedup vs baseline: 3.4138x; 1.6874x over previous
//
#include <hip/hip_runtime.h>
#include <hip/hip_bf16.h>

// Problem constants
#define B_   4
#define N_   160
#define D_   64
#define ZI_  64
#define H1_  128
#define H2_  64
#define L_   4
#define LE_  8

typedef __bf16 bf16x8 __attribute__((ext_vector_type(8)));
typedef float  f32x4  __attribute__((ext_vector_type(4)));
typedef unsigned int u32x4 __attribute__((ext_vector_type(4)));

// 16-lane-group sum via pure-VALU DPP (no DS ops, no lgkm waits):
// quad_perm xor1 (0xB1), quad_perm xor2 (0x4E), row_ror:4 (0x124),
// row_ror:8 (0x128). After the chain every lane of each 16-lane group
// holds the group sum (rotation tree-reduce).
#define DPP_ADD_(p, ctrl)                                                   \
    do {                                                                    \
        int _t = __builtin_amdgcn_update_dpp(0, __float_as_int(p), (ctrl),  \
                                             0xF, 0xF, true);               \
        (p) += __int_as_float(_t);                                          \
    } while (0)

// ---------------------------------------------------------------------------
// Stage A: per-(b,i) precompute (scalar; ~3 µs). Unchanged.
//   ui[b,i,h]   = ne[b,i]@Wi1[:64] + z_intra[b]@Wi1[128:192] + bi1      (fp32)
//   uq[b,l,i,h] = ne[b,i]@Wl1[:64] + z_inter[b]@Wl1[128:192] + lag[l]@Wl1_l + bl1
//   u rows stored PRE-PERMUTED within each 8-chunk (evens then odds) so
//   stage_b fetches MFMA-A even/odd halves as two straight f32x4 loads.
//   vpi/vpl = bf16 j-panels, PRE-SWIZZLED (elem h -> granule (h>>3)^(i&7)).
// Blocks 0/1 pack the per-branch setup BLOB (global, L2-hot for stage_b):
//   [ W2 bf16 fragment-ordered 16384 B | b2 fp32 512 B | w3 fp32 512 B |
//     b3 fp32 4 B | pad -> 20480 B ]
// ---------------------------------------------------------------------------
__global__ __launch_bounds__(128) void stage_a(
    const float* __restrict__ ne,
    const float* __restrict__ zi,
    const float* __restrict__ ze,
    const float* __restrict__ lag,
    const float* __restrict__ Wi1,
    const float* __restrict__ bi1,
    const float* __restrict__ Wl1,
    const float* __restrict__ bl1,
    const float* __restrict__ Wi2,
    const float* __restrict__ bi2,
    const float* __restrict__ Wi3,
    const float* __restrict__ bi3,
    const float* __restrict__ Wl2,
    const float* __restrict__ bl2,
    const float* __restrict__ Wl3,
    const float* __restrict__ bl3,
    float* __restrict__ ui, float* __restrict__ uq,
    __bf16* __restrict__ vpi, __bf16* __restrict__ vpl,
    char* __restrict__ blob_i, char* __restrict__ blob_l)
{
    const int bi = blockIdx.x;       // b*N + i
    const int b  = bi / N_;
    const int h  = threadIdx.x;      // 0..127

    const float* nerow = ne + bi * D_;

    float pi_ = 0.f, pj_ = 0.f, qi_ = 0.f, qj_ = 0.f;
#pragma unroll 16
    for (int d = 0; d < D_; ++d) {
        const float a = nerow[d];
        pi_ += a * Wi1[d * H1_ + h];
        pj_ += a * Wi1[(D_ + d) * H1_ + h];
        qi_ += a * Wl1[d * H1_ + h];
        qj_ += a * Wl1[(D_ + d) * H1_ + h];
    }
    float pz = 0.f, qz = 0.f;
#pragma unroll 16
    for (int z = 0; z < ZI_; ++z) {
        pz += zi[b * ZI_ + z] * Wi1[(2 * D_ + z) * H1_ + h];
        qz += ze[b * ZI_ + z] * Wl1[(2 * D_ + z) * H1_ + h];
    }

    // Even/odd permuted store index (see header).
    const int r7 = h & 7;
    const int hp = (h & ~7) | ((r7 & 1) ? (4 + (r7 >> 1)) : (r7 >> 1));

    ui[bi * H1_ + hp] = pi_ + pz + bi1[h];

    // Pre-swizzled panel store (row&7 == bi&7 since N is a multiple of 8).
    const int hsw = (((h >> 3) ^ (bi & 7)) << 3) | (h & 7);
    vpi[bi * H1_ + hsw] = (__bf16)pj_;
    vpl[bi * H1_ + hsw] = (__bf16)qj_;

    const float qbase = qi_ + qz + bl1[h];
#pragma unroll
    for (int l = 0; l < L_; ++l) {
        float ql = 0.f;
#pragma unroll
        for (int e = 0; e < LE_; ++e)
            ql += lag[l * LE_ + e] * Wl1[(2 * D_ + ZI_ + e) * H1_ + h];
        uq[((b * L_ + l) * N_ + (bi % N_)) * H1_ + hp] = qbase + ql;
    }

    // Pack the setup blob for stage_b.
    if (bi < 2) {
        const float* Wsrc = (bi == 0) ? Wi2 : Wl2;
        char* blob = (bi == 0) ? blob_i : blob_l;
        __bf16* Wdst = (__bf16*)blob;
        // W2 -> bf16 fragment layout: chunk fc = (kt*4+ct)*64 + lane holds
        // the 8 values lane needs for fragment (kt,ct).
#pragma unroll
        for (int r = 0; r < 8; ++r) {
            const int fc = h + 128 * r;
            const int kt = fc >> 8, ct = (fc >> 6) & 3;
            const int q = (fc >> 4) & 3, c = fc & 15;
            bf16x8 t;
#pragma unroll
            for (int j = 0; j < 8; ++j)
                t[j] = (__bf16)Wsrc[(32 * kt + 8 * q + j) * H2_ + 16 * ct + c];
            *(bf16x8*)(Wdst + fc * 8) = t;
        }
        // Biases + w3 (fp32) appended.
        float* bdst = (float*)(blob + 16384);
        const float* b2s = (bi == 0) ? bi2 : bl2;
        const float* w3s = (bi == 0) ? Wi3 : Wl3;
        const float* b3s = (bi == 0) ? bi3 : bl3;
        if (h < H2_) bdst[h] = b2s[h];
        if (h < H2_) bdst[128 + h] = w3s[h];
        if (h == 0)  bdst[256] = b3s[0];
    }
}

// ---------------------------------------------------------------------------
// Stage B (R16): R14's proven full-row body, 4-blocks/CU occupancy.
// R14 PMCs: VALUBusy 53.5%, MfmaUtil 12.9%, HBM ~0 (L2-resident), VGPR 84,
// 12 waves/CU -> VALU-issue-bound with 46% dependency stall. R15 lesson:
// never bound VGPRs below a measured allocation (spill -> 500 MB scratch).
// Changes vs R14:
//  (a) LDS = panel ONLY (40960 B): 4 blocks/CU x 40960 = exactly 160 KiB.
//      u moves to registers via 8 global f32x4 loads from the wave's own
//      row (L2-hot, issued before the barrier). VGPR 84 -> 4 waves/SIMD,
//      so LDS and VGPR now agree at 16 waves/CU (1.33x R14). 800 blocks /
//      (4x256 slots) = 0.78 -> single occupancy round.
//  (b) bf16 pack via plain (__bf16) pair casts -> v_cvt_pk_bf16_f32.
//  (c) epilogue 16-lane reduce via DPP add chain (quad_perm/row_ror):
//      pure VALU, removes 160 ds_bpermute + lgkm waits per wave.
// __launch_bounds__(256,4): budget 128 >= demand ~90, no spill risk.
// MFMA 16x16x32 layouts (HW-verified):
//   A: lane holds A[m=lane&15][k=8*(lane>>4)+j]
//   B: lane holds B[k=8*(lane>>4)+j][n=lane&15]
//   C/D: lane holds D[row=4*(lane>>4)+reg][col=lane&15]
// ---------------------------------------------------------------------------
__global__ __launch_bounds__(256, 4) void stage_b(
    const float* __restrict__ ui, const float* __restrict__ uq,
    const __bf16* __restrict__ vpi, const __bf16* __restrict__ vpl,
    const char* __restrict__ blob_i, const char* __restrict__ blob_l,
    float* __restrict__ out)
{
    __shared__ __align__(16) char lds[40960];   // full 160x128 bf16 panel

    const int t    = threadIdx.x;
    const int wid  = t >> 6;         // 0..3 (row within quad)
    const int lane = t & 63;
    const int q = lane >> 4;
    const int c = lane & 15;

    const int blk  = blockIdx.x;     // 0..799
    const int row0 = blk * 4;        // first row of quad
    const int wave = row0 + wid;     // row id 0..3199

    // Block-uniform sources.
    const __bf16* psrc;
    const char*   bsrc;
    const float*  usrc;
    if (blk < 160) {                 // intra (rows 0..639)
        psrc = vpi + (blk / 40) * (N_ * H1_);
        bsrc = blob_i;
        usrc = ui + row0 * H1_;
    } else {                         // inter (rows 640..3199)
        psrc = vpl + ((blk - 160) / 160) * (N_ * H1_);
        bsrc = blob_l;
        usrc = uq + (row0 - B_ * N_) * H1_;
    }

    // 1) DMA burst: full panel, 40 KiB in 1 KiB granules over 4 waves.
    for (int g = wid; g < 40; g += 4) {
        __builtin_amdgcn_global_load_lds(
            (const __attribute__((address_space(1))) void*)
                ((const char*)psrc + (g << 10) + lane * 16),
            (__attribute__((address_space(3))) void*)(lds + (g << 10)),
            16, 0, 0);
    }

    // 2) Register-resident setup straight from global (L2-hot; latency
    //    overlaps the DMA drain). W2 fragments, biases, and this wave's
    //    own u row (permuted: evens at +0..3, odds at +4..7 per 8-chunk).
    bf16x8 bfr[4][4];
#pragma unroll
    for (int kt = 0; kt < 4; ++kt)
#pragma unroll
        for (int ct = 0; ct < 4; ++ct)
            bfr[kt][ct] = *(const bf16x8*)(bsrc + ((kt * 4 + ct) * 64 + lane) * 16);

    const float* bf32 = (const float*)(bsrc + 16384);
    float b2c[4], w3c[4];
#pragma unroll
    for (int ct = 0; ct < 4; ++ct) {
        b2c[ct] = bf32[16 * ct + c];
        w3c[ct] = bf32[128 + 16 * ct + c];
    }
    const float b3f = bf32[256];

    const float* urow = usrc + wid * H1_;
    f32x4 ue[4], uo[4];
#pragma unroll
    for (int kt = 0; kt < 4; ++kt) {
        ue[kt] = *(const f32x4*)(urow + 32 * kt + 8 * q);
        uo[kt] = *(const f32x4*)(urow + 32 * kt + 8 * q + 4);
    }

    const int  i     = (wave < B_ * N_ ? wave : wave - B_ * N_) % N_;
    const long obase = (long)wave * N_;   // holds for both branches

    __syncthreads();   // drains DMA (vmcnt) for all waves

    const __bf16* panel = (const __bf16*)lds;

    // 3) Full-row tile loop: 10 j-tiles.
    for (int jt = 0; jt < 10; ++jt) {
        const __bf16* prow = panel + (16 * jt + c) * H1_;
        f32x4 acc[4];
#pragma unroll
        for (int ct = 0; ct < 4; ++ct)
            acc[ct] = (f32x4){b2c[ct], b2c[ct], b2c[ct], b2c[ct]};

#pragma unroll
        for (int kt = 0; kt < 4; ++kt) {
            const u32x4 vw = *(const u32x4*)(prow + (((4 * kt + q) ^ (c & 7)) << 3));
            bf16x8 av;
#pragma unroll
            for (int d = 0; d < 4; ++d) {
                const unsigned w = vw[d];
                const float lo = __uint_as_float(w << 16) + ue[kt][d];
                const float hi = __uint_as_float(w & 0xffff0000u) + uo[kt][d];
                av[2 * d]     = (__bf16)fmaxf(lo, 0.f);   // pair -> v_cvt_pk_bf16_f32
                av[2 * d + 1] = (__bf16)fmaxf(hi, 0.f);
            }
#pragma unroll
            for (int ct = 0; ct < 4; ++ct)
                acc[ct] = __builtin_amdgcn_mfma_f32_16x16x32_bf16(
                    av, bfr[kt][ct], acc[ct], 0, 0, 0);
        }

        // Epilogue: logit[r] = b3 + sum_col relu(H2pre) * w3 (b2 in acc).
        // 16-lane-group sum via DPP rotation tree (pure VALU, no DS).
        float logit[4];
#pragma unroll
        for (int r = 0; r < 4; ++r) {
            float p = 0.f;
#pragma unroll
            for (int ct = 0; ct < 4; ++ct)
                p += fmaxf(acc[ct][r], 0.f) * w3c[ct];
            DPP_ADD_(p, 0xB1);    // quad_perm [1,0,3,2]  (xor1)
            DPP_ADD_(p, 0x4E);    // quad_perm [2,3,0,1]  (xor2)
            DPP_ADD_(p, 0x124);   // row_ror:4
            DPP_ADD_(p, 0x128);   // row_ror:8
            logit[r] = p;
        }

        if (c < 4) {
            const int j = 16 * jt + 4 * q + c;
            const float lg = logit[c] + b3f;
            const float s = (j == i) ? 0.f : 1.f / (1.f + __expf(-lg));
            out[obase + j] = s;
        }
    }
}

// ---------------------------------------------------------------------------
extern "C" void kernel_launch(void* const* d_in, const int* in_sizes, int n_in,
                              void* d_out, int out_size, void* d_ws, size_t ws_size,
                              hipStream_t stream) {
    const float* ne  = (const float*)d_in[0];
    const float* zi  = (const float*)d_in[1];
    const float* ze  = (const float*)d_in[2];
    const float* lag = (const float*)d_in[3];
    const float* Wi1 = (const float*)d_in[4];
    const float* bi1 = (const float*)d_in[5];
    const float* Wi2 = (const float*)d_in[6];
    const float* bi2 = (const float*)d_in[7];
    const float* Wi3 = (const float*)d_in[8];
    const float* bi3 = (const float*)d_in[9];
    const float* Wl1 = (const float*)d_in[10];
    const float* bl1 = (const float*)d_in[11];
    const float* Wl2 = (const float*)d_in[12];
    const float* bl2 = (const float*)d_in[13];
    const float* Wl3 = (const float*)d_in[14];
    const float* bl3 = (const float*)d_in[15];

    float*  ws     = (float*)d_ws;
    float*  ui     = ws;                        // 640*128 fp32 (permuted rows)
    float*  uqw    = ws + 81920;                // 2560*128 fp32 (permuted rows)
    __bf16* vpi    = (__bf16*)(ws + 409600);    // 640*128 bf16 (pre-swizzled)
    __bf16* vpl    = vpi + 81920;               // 640*128 bf16 (pre-swizzled)
    char*   blob_i = (char*)d_ws + 1966080;     // 20480 B setup blob (intra)
    char*   blob_l = blob_i + 20480;            // 20480 B setup blob (inter)

    stage_a<<<B_ * N_, 128, 0, stream>>>(ne, zi, ze, lag, Wi1, bi1, Wl1, bl1,
                                         Wi2, bi2, Wi3, bi3, Wl2, bl2, Wl3, bl3,
                                         ui, uqw, vpi, vpl, blob_i, blob_l);

    stage_b<<<800, 256, 0, stream>>>(
        ui, uqw, vpi, vpl, blob_i, blob_l,
        (float*)d_out);
}

// Round 8
// 110.617 us; speedup vs baseline: 4.2967x; 1.2586x over previous
//
#include <hip/hip_runtime.h>
#include <hip/hip_bf16.h>

// Problem constants
#define B_   4
#define N_   160
#define D_   64
#define ZI_  64
#define H1_  128
#define H2_  64
#define L_   4
#define LE_  8

typedef __bf16 bf16x8 __attribute__((ext_vector_type(8)));
typedef float  f32x4  __attribute__((ext_vector_type(4)));
typedef unsigned int u32x4 __attribute__((ext_vector_type(4)));

// 16-lane-group sum via pure-VALU DPP (no DS ops, no lgkm waits):
// quad_perm xor1 (0xB1), quad_perm xor2 (0x4E), row_ror:4 (0x124),
// row_ror:8 (0x128). After the chain every lane of each 16-lane group
// holds the group sum. Verified correct in R16 (passed, same absmax).
#define DPP_ADD_(p, ctrl)                                                   \
    do {                                                                    \
        int _t = __builtin_amdgcn_update_dpp(0, __float_as_int(p), (ctrl),  \
                                             0xF, 0xF, true);               \
        (p) += __int_as_float(_t);                                          \
    } while (0)

// ---------------------------------------------------------------------------
// Stage A: per-(b,i) precompute (scalar; ~3 µs). Unchanged.
//   ui[b,i,h]   = ne[b,i]@Wi1[:64] + z_intra[b]@Wi1[128:192] + bi1      (fp32)
//   uq[b,l,i,h] = ne[b,i]@Wl1[:64] + z_inter[b]@Wl1[128:192] + lag[l]@Wl1_l + bl1
//   u rows stored PRE-PERMUTED within each 8-chunk (evens then odds) so
//   stage_b fetches MFMA-A even/odd halves as two straight ds_read_b128.
//   vpi/vpl = bf16 j-panels, PRE-SWIZZLED (elem h -> granule (h>>3)^(i&7)).
// Blocks 0/1 pack the per-branch setup BLOB (global, L2-hot for stage_b):
//   [ W2 bf16 fragment-ordered 16384 B | b2 fp32 512 B | w3 fp32 512 B |
//     b3 fp32 4 B | pad -> 20480 B ]
// ---------------------------------------------------------------------------
__global__ __launch_bounds__(128) void stage_a(
    const float* __restrict__ ne,
    const float* __restrict__ zi,
    const float* __restrict__ ze,
    const float* __restrict__ lag,
    const float* __restrict__ Wi1,
    const float* __restrict__ bi1,
    const float* __restrict__ Wl1,
    const float* __restrict__ bl1,
    const float* __restrict__ Wi2,
    const float* __restrict__ bi2,
    const float* __restrict__ Wi3,
    const float* __restrict__ bi3,
    const float* __restrict__ Wl2,
    const float* __restrict__ bl2,
    const float* __restrict__ Wl3,
    const float* __restrict__ bl3,
    float* __restrict__ ui, float* __restrict__ uq,
    __bf16* __restrict__ vpi, __bf16* __restrict__ vpl,
    char* __restrict__ blob_i, char* __restrict__ blob_l)
{
    const int bi = blockIdx.x;       // b*N + i
    const int b  = bi / N_;
    const int h  = threadIdx.x;      // 0..127

    const float* nerow = ne + bi * D_;

    float pi_ = 0.f, pj_ = 0.f, qi_ = 0.f, qj_ = 0.f;
#pragma unroll 16
    for (int d = 0; d < D_; ++d) {
        const float a = nerow[d];
        pi_ += a * Wi1[d * H1_ + h];
        pj_ += a * Wi1[(D_ + d) * H1_ + h];
        qi_ += a * Wl1[d * H1_ + h];
        qj_ += a * Wl1[(D_ + d) * H1_ + h];
    }
    float pz = 0.f, qz = 0.f;
#pragma unroll 16
    for (int z = 0; z < ZI_; ++z) {
        pz += zi[b * ZI_ + z] * Wi1[(2 * D_ + z) * H1_ + h];
        qz += ze[b * ZI_ + z] * Wl1[(2 * D_ + z) * H1_ + h];
    }

    // Even/odd permuted store index (see header).
    const int r7 = h & 7;
    const int hp = (h & ~7) | ((r7 & 1) ? (4 + (r7 >> 1)) : (r7 >> 1));

    ui[bi * H1_ + hp] = pi_ + pz + bi1[h];

    // Pre-swizzled panel store (row&7 == bi&7 since N is a multiple of 8).
    const int hsw = (((h >> 3) ^ (bi & 7)) << 3) | (h & 7);
    vpi[bi * H1_ + hsw] = (__bf16)pj_;
    vpl[bi * H1_ + hsw] = (__bf16)qj_;

    const float qbase = qi_ + qz + bl1[h];
#pragma unroll
    for (int l = 0; l < L_; ++l) {
        float ql = 0.f;
#pragma unroll
        for (int e = 0; e < LE_; ++e)
            ql += lag[l * LE_ + e] * Wl1[(2 * D_ + ZI_ + e) * H1_ + h];
        uq[((b * L_ + l) * N_ + (bi % N_)) * H1_ + hp] = qbase + ql;
    }

    // Pack the setup blob for stage_b.
    if (bi < 2) {
        const float* Wsrc = (bi == 0) ? Wi2 : Wl2;
        char* blob = (bi == 0) ? blob_i : blob_l;
        __bf16* Wdst = (__bf16*)blob;
        // W2 -> bf16 fragment layout: chunk fc = (kt*4+ct)*64 + lane holds
        // the 8 values lane needs for fragment (kt,ct).
#pragma unroll
        for (int r = 0; r < 8; ++r) {
            const int fc = h + 128 * r;
            const int kt = fc >> 8, ct = (fc >> 6) & 3;
            const int q = (fc >> 4) & 3, c = fc & 15;
            bf16x8 t;
#pragma unroll
            for (int j = 0; j < 8; ++j)
                t[j] = (__bf16)Wsrc[(32 * kt + 8 * q + j) * H2_ + 16 * ct + c];
            *(bf16x8*)(Wdst + fc * 8) = t;
        }
        // Biases + w3 (fp32) appended.
        float* bdst = (float*)(blob + 16384);
        const float* b2s = (bi == 0) ? bi2 : bl2;
        const float* w3s = (bi == 0) ? Wi3 : Wl3;
        const float* b3s = (bi == 0) ? bi3 : bl3;
        if (h < H2_) bdst[h] = b2s[h];
        if (h < H2_) bdst[128 + h] = w3s[h];
        if (h == 0)  bdst[256] = b3s[0];
    }
}

// ---------------------------------------------------------------------------
// Stage B (R17): the proven no-spill R14 structure + the two VALU cuts.
// R15/R16 lesson (counter-verified): any VGPR cap below ~170 makes the
// unified-file VGPR/AGPR split starve the VGPR side -> scratch spill
// (FETCH/WRITE jump from KB to MB scale). So occupancy stays at
// __launch_bounds__(256,3) / 3 blocks/CU; we attack VALU count instead:
//  (b) bf16 pack via plain (__bf16) pair casts -> v_cvt_pk_bf16_f32
//      (R14 used __float22bfloat162_rn, potentially software RNE).
//  (c) epilogue 16-lane reduce via DPP add chain (quad_perm/row_ror):
//      pure VALU, removes 160 ds_bpermute + lgkm waits per wave.
// Everything else identical to R14: 800 blocks x 256 thr, full-row waves,
// LDS 43008 B = [panel 40960: 160x128 bf16 pre-swizzled][u 2048], bfr from
// global blob (L2-hot), u from LDS (even/odd permuted rows).
// Spill gate: FETCH/WRITE must stay KB-scale; if MB-scale, revert.
// MFMA 16x16x32 layouts (HW-verified):
//   A: lane holds A[m=lane&15][k=8*(lane>>4)+j]
//   B: lane holds B[k=8*(lane>>4)+j][n=lane&15]
//   C/D: lane holds D[row=4*(lane>>4)+reg][col=lane&15]
// ---------------------------------------------------------------------------
__global__ __launch_bounds__(256, 3) void stage_b(
    const float* __restrict__ ui, const float* __restrict__ uq,
    const __bf16* __restrict__ vpi, const __bf16* __restrict__ vpl,
    const char* __restrict__ blob_i, const char* __restrict__ blob_l,
    float* __restrict__ out)
{
    __shared__ __align__(16) char lds[43008];

    const int t    = threadIdx.x;
    const int wid  = t >> 6;         // 0..3 (row within quad)
    const int lane = t & 63;
    const int q = lane >> 4;
    const int c = lane & 15;

    const int blk  = blockIdx.x;     // 0..799
    const int row0 = blk * 4;        // first row of quad
    const int wave = row0 + wid;     // row id 0..3199

    // Block-uniform sources.
    const __bf16* psrc;
    const char*   bsrc;
    const float*  usrc;
    if (blk < 160) {                 // intra (rows 0..639)
        psrc = vpi + (blk / 40) * (N_ * H1_);
        bsrc = blob_i;
        usrc = ui + row0 * H1_;
    } else {                         // inter (rows 640..3199)
        psrc = vpl + ((blk - 160) / 160) * (N_ * H1_);
        bsrc = blob_l;
        usrc = uq + (row0 - B_ * N_) * H1_;
    }

    // 1) DMA burst: 42 KiB in 1 KiB granules over 4 waves (panel 0..39, u 40..41).
    for (int g = wid; g < 42; g += 4) {
        const char* src = (g < 40) ? (const char*)psrc + (g << 10)
                                   : (const char*)usrc + ((g - 40) << 10);
        __builtin_amdgcn_global_load_lds(
            (const __attribute__((address_space(1))) void*)(src + lane * 16),
            (__attribute__((address_space(3))) void*)(lds + (g << 10)),
            16, 0, 0);
    }

    // 2) W2 fragments + biases straight from global blob (L2-hot, once per
    //    wave; latency overlaps the DMA drain).
    bf16x8 bfr[4][4];
#pragma unroll
    for (int kt = 0; kt < 4; ++kt)
#pragma unroll
        for (int ct = 0; ct < 4; ++ct)
            bfr[kt][ct] = *(const bf16x8*)(bsrc + ((kt * 4 + ct) * 64 + lane) * 16);

    const float* bf32 = (const float*)(bsrc + 16384);
    float b2c[4], w3c[4];
#pragma unroll
    for (int ct = 0; ct < 4; ++ct) {
        b2c[ct] = bf32[16 * ct + c];
        w3c[ct] = bf32[128 + 16 * ct + c];
    }
    const float b3f = bf32[256];

    const int  i     = (wave < B_ * N_ ? wave : wave - B_ * N_) % N_;
    const long obase = (long)wave * N_;   // holds for both branches

    __syncthreads();   // drains DMA (vmcnt) for all waves

    // 3) u halves once from LDS (permuted rows: evens at +0..3, odds +4..7).
    const float* ubase = (const float*)(lds + 40960) + wid * H1_;
    f32x4 ue[4], uo[4];
#pragma unroll
    for (int kt = 0; kt < 4; ++kt) {
        ue[kt] = *(const f32x4*)(ubase + 32 * kt + 8 * q);
        uo[kt] = *(const f32x4*)(ubase + 32 * kt + 8 * q + 4);
    }

    const __bf16* panel = (const __bf16*)lds;

    // 4) Full-row tile loop: 10 j-tiles.
    for (int jt = 0; jt < 10; ++jt) {
        const __bf16* prow = panel + (16 * jt + c) * H1_;
        f32x4 acc[4];
#pragma unroll
        for (int ct = 0; ct < 4; ++ct)
            acc[ct] = (f32x4){b2c[ct], b2c[ct], b2c[ct], b2c[ct]};

#pragma unroll
        for (int kt = 0; kt < 4; ++kt) {
            const u32x4 vw = *(const u32x4*)(prow + (((4 * kt + q) ^ (c & 7)) << 3));
            bf16x8 av;
#pragma unroll
            for (int d = 0; d < 4; ++d) {
                const unsigned w = vw[d];
                const float lo = __uint_as_float(w << 16) + ue[kt][d];
                const float hi = __uint_as_float(w & 0xffff0000u) + uo[kt][d];
                av[2 * d]     = (__bf16)fmaxf(lo, 0.f);   // pair -> v_cvt_pk_bf16_f32
                av[2 * d + 1] = (__bf16)fmaxf(hi, 0.f);
            }
#pragma unroll
            for (int ct = 0; ct < 4; ++ct)
                acc[ct] = __builtin_amdgcn_mfma_f32_16x16x32_bf16(
                    av, bfr[kt][ct], acc[ct], 0, 0, 0);
        }

        // Epilogue: logit[r] = b3 + sum_col relu(H2pre) * w3 (b2 in acc).
        // 16-lane-group sum via DPP rotation tree (pure VALU, no DS).
        float logit[4];
#pragma unroll
        for (int r = 0; r < 4; ++r) {
            float p = 0.f;
#pragma unroll
            for (int ct = 0; ct < 4; ++ct)
                p += fmaxf(acc[ct][r], 0.f) * w3c[ct];
            DPP_ADD_(p, 0xB1);    // quad_perm [1,0,3,2]  (xor1)
            DPP_ADD_(p, 0x4E);    // quad_perm [2,3,0,1]  (xor2)
            DPP_ADD_(p, 0x124);   // row_ror:4
            DPP_ADD_(p, 0x128);   // row_ror:8
            logit[r] = p;
        }

        if (c < 4) {
            const int j = 16 * jt + 4 * q + c;
            const float lg = logit[c] + b3f;
            const float s = (j == i) ? 0.f : 1.f / (1.f + __expf(-lg));
            out[obase + j] = s;
        }
    }
}

// ---------------------------------------------------------------------------
extern "C" void kernel_launch(void* const* d_in, const int* in_sizes, int n_in,
                              void* d_out, int out_size, void* d_ws, size_t ws_size,
                              hipStream_t stream) {
    const float* ne  = (const float*)d_in[0];
    const float* zi  = (const float*)d_in[1];
    const float* ze  = (const float*)d_in[2];
    const float* lag = (const float*)d_in[3];
    const float* Wi1 = (const float*)d_in[4];
    const float* bi1 = (const float*)d_in[5];
    const float* Wi2 = (const float*)d_in[6];
    const float* bi2 = (const float*)d_in[7];
    const float* Wi3 = (const float*)d_in[8];
    const float* bi3 = (const float*)d_in[9];
    const float* Wl1 = (const float*)d_in[10];
    const float* bl1 = (const float*)d_in[11];
    const float* Wl2 = (const float*)d_in[12];
    const float* bl2 = (const float*)d_in[13];
    const float* Wl3 = (const float*)d_in[14];
    const float* bl3 = (const float*)d_in[15];

    float*  ws     = (float*)d_ws;
    float*  ui     = ws;                        // 640*128 fp32 (permuted rows)
    float*  uqw    = ws + 81920;                // 2560*128 fp32 (permuted rows)
    __bf16* vpi    = (__bf16*)(ws + 409600);    // 640*128 bf16 (pre-swizzled)
    __bf16* vpl    = vpi + 81920;               // 640*128 bf16 (pre-swizzled)
    char*   blob_i = (char*)d_ws + 1966080;     // 20480 B setup blob (intra)
    char*   blob_l = blob_i + 20480;            // 20480 B setup blob (inter)

    stage_a<<<B_ * N_, 128, 0, stream>>>(ne, zi, ze, lag, Wi1, bi1, Wl1, bl1,
                                         Wi2, bi2, Wi3, bi3, Wl2, bl2, Wl3, bl3,
                                         ui, uqw, vpi, vpl, blob_i, blob_l);

    stage_b<<<800, 256, 0, stream>>>(
        ui, uqw, vpi, vpl, blob_i, blob_l,
        (float*)d_out);
}

// Round 9
// 109.868 us; speedup vs baseline: 4.3260x; 1.0068x over previous
//
#include <hip/hip_runtime.h>
#include <hip/hip_bf16.h>

// Problem constants
#define B_   4
#define N_   160
#define D_   64
#define ZI_  64
#define H1_  128
#define H2_  64
#define L_   4
#define LE_  8

typedef __bf16 bf16x8 __attribute__((ext_vector_type(8)));
typedef float  f32x4  __attribute__((ext_vector_type(4)));
typedef unsigned int u32x4 __attribute__((ext_vector_type(4)));

// 16-lane-group sum via pure-VALU DPP (no DS ops, no lgkm waits):
// quad_perm xor1 (0xB1), quad_perm xor2 (0x4E), row_ror:4 (0x124),
// row_ror:8 (0x128). After the chain every lane of each 16-lane group
// holds the group sum. Verified correct in R16/R17.
#define DPP_ADD_(p, ctrl)                                                   \
    do {                                                                    \
        int _t = __builtin_amdgcn_update_dpp(0, __float_as_int(p), (ctrl),  \
                                             0xF, 0xF, true);               \
        (p) += __int_as_float(_t);                                          \
    } while (0)

// ---------------------------------------------------------------------------
// Stage A: per-(b,i) precompute (scalar; ~3 µs). Unchanged.
//   ui[b,i,h]   = ne[b,i]@Wi1[:64] + z_intra[b]@Wi1[128:192] + bi1      (fp32)
//   uq[b,l,i,h] = ne[b,i]@Wl1[:64] + z_inter[b]@Wl1[128:192] + lag[l]@Wl1_l + bl1
//   u rows stored PRE-PERMUTED within each 8-chunk (evens then odds) so
//   stage_b fetches MFMA-A even/odd halves as two straight ds_read_b128.
//   vpi/vpl = bf16 j-panels, PRE-SWIZZLED (elem h -> granule (h>>3)^(i&7)).
// Blocks 0/1 pack the per-branch setup BLOB (global, L2-hot for stage_b):
//   [ W2 bf16 fragment-ordered 16384 B | b2 fp32 512 B | w3 fp32 512 B |
//     b3 fp32 4 B | pad -> 20480 B ]
// ---------------------------------------------------------------------------
__global__ __launch_bounds__(128) void stage_a(
    const float* __restrict__ ne,
    const float* __restrict__ zi,
    const float* __restrict__ ze,
    const float* __restrict__ lag,
    const float* __restrict__ Wi1,
    const float* __restrict__ bi1,
    const float* __restrict__ Wl1,
    const float* __restrict__ bl1,
    const float* __restrict__ Wi2,
    const float* __restrict__ bi2,
    const float* __restrict__ Wi3,
    const float* __restrict__ bi3,
    const float* __restrict__ Wl2,
    const float* __restrict__ bl2,
    const float* __restrict__ Wl3,
    const float* __restrict__ bl3,
    float* __restrict__ ui, float* __restrict__ uq,
    __bf16* __restrict__ vpi, __bf16* __restrict__ vpl,
    char* __restrict__ blob_i, char* __restrict__ blob_l)
{
    const int bi = blockIdx.x;       // b*N + i
    const int b  = bi / N_;
    const int h  = threadIdx.x;      // 0..127

    const float* nerow = ne + bi * D_;

    float pi_ = 0.f, pj_ = 0.f, qi_ = 0.f, qj_ = 0.f;
#pragma unroll 16
    for (int d = 0; d < D_; ++d) {
        const float a = nerow[d];
        pi_ += a * Wi1[d * H1_ + h];
        pj_ += a * Wi1[(D_ + d) * H1_ + h];
        qi_ += a * Wl1[d * H1_ + h];
        qj_ += a * Wl1[(D_ + d) * H1_ + h];
    }
    float pz = 0.f, qz = 0.f;
#pragma unroll 16
    for (int z = 0; z < ZI_; ++z) {
        pz += zi[b * ZI_ + z] * Wi1[(2 * D_ + z) * H1_ + h];
        qz += ze[b * ZI_ + z] * Wl1[(2 * D_ + z) * H1_ + h];
    }

    // Even/odd permuted store index (see header).
    const int r7 = h & 7;
    const int hp = (h & ~7) | ((r7 & 1) ? (4 + (r7 >> 1)) : (r7 >> 1));

    ui[bi * H1_ + hp] = pi_ + pz + bi1[h];

    // Pre-swizzled panel store (row&7 == bi&7 since N is a multiple of 8).
    const int hsw = (((h >> 3) ^ (bi & 7)) << 3) | (h & 7);
    vpi[bi * H1_ + hsw] = (__bf16)pj_;
    vpl[bi * H1_ + hsw] = (__bf16)qj_;

    const float qbase = qi_ + qz + bl1[h];
#pragma unroll
    for (int l = 0; l < L_; ++l) {
        float ql = 0.f;
#pragma unroll
        for (int e = 0; e < LE_; ++e)
            ql += lag[l * LE_ + e] * Wl1[(2 * D_ + ZI_ + e) * H1_ + h];
        uq[((b * L_ + l) * N_ + (bi % N_)) * H1_ + hp] = qbase + ql;
    }

    // Pack the setup blob for stage_b.
    if (bi < 2) {
        const float* Wsrc = (bi == 0) ? Wi2 : Wl2;
        char* blob = (bi == 0) ? blob_i : blob_l;
        __bf16* Wdst = (__bf16*)blob;
        // W2 -> bf16 fragment layout: chunk fc = (kt*4+ct)*64 + lane holds
        // the 8 values lane needs for fragment (kt,ct).
#pragma unroll
        for (int r = 0; r < 8; ++r) {
            const int fc = h + 128 * r;
            const int kt = fc >> 8, ct = (fc >> 6) & 3;
            const int q = (fc >> 4) & 3, c = fc & 15;
            bf16x8 t;
#pragma unroll
            for (int j = 0; j < 8; ++j)
                t[j] = (__bf16)Wsrc[(32 * kt + 8 * q + j) * H2_ + 16 * ct + c];
            *(bf16x8*)(Wdst + fc * 8) = t;
        }
        // Biases + w3 (fp32) appended.
        float* bdst = (float*)(blob + 16384);
        const float* b2s = (bi == 0) ? bi2 : bl2;
        const float* w3s = (bi == 0) ? Wi3 : Wl3;
        const float* b3s = (bi == 0) ? bi3 : bl3;
        if (h < H2_) bdst[h] = b2s[h];
        if (h < H2_) bdst[128 + h] = w3s[h];
        if (h == 0)  bdst[256] = b3s[0];
    }
}

// ---------------------------------------------------------------------------
// Stage B (R18): R17 + software-pipelined panel reads across jt (G15/T14).
// R17 counters: no spill (FETCH/WRITE KB-scale), stage_b ~22.5us, occupancy
// locked at 3 waves/SIMD (R15/R16: any VGPR cap <170 spills). Remaining
// stall theory: each jt starts with 4 dependent ds_read_b128 (~120cyc)
// exposed at every jt boundary (compiler won't hoist across the epilogue's
// conditional store). Fix: rotate register buffer vwb[4] holding this jt's
// fragments; issue jt+1's 4 reads at loop-body TOP, ~300cyc before use.
// +32 VGPR (~116 total), far under the (256,3)=170 budget -> no spill.
// Spill gate: FETCH/WRITE must stay KB-scale; if MB-scale, revert.
// Everything else identical to R17: 800 blocks x 256 thr, full-row waves,
// LDS 43008 B = [panel 40960: 160x128 bf16 pre-swizzled][u 2048], bfr from
// global blob (L2-hot), u from LDS (even/odd permuted rows), v_cvt_pk pack,
// DPP epilogue reduce.
// MFMA 16x16x32 layouts (HW-verified):
//   A: lane holds A[m=lane&15][k=8*(lane>>4)+j]
//   B: lane holds B[k=8*(lane>>4)+j][n=lane&15]
//   C/D: lane holds D[row=4*(lane>>4)+reg][col=lane&15]
// ---------------------------------------------------------------------------
__global__ __launch_bounds__(256, 3) void stage_b(
    const float* __restrict__ ui, const float* __restrict__ uq,
    const __bf16* __restrict__ vpi, const __bf16* __restrict__ vpl,
    const char* __restrict__ blob_i, const char* __restrict__ blob_l,
    float* __restrict__ out)
{
    __shared__ __align__(16) char lds[43008];

    const int t    = threadIdx.x;
    const int wid  = t >> 6;         // 0..3 (row within quad)
    const int lane = t & 63;
    const int q = lane >> 4;
    const int c = lane & 15;

    const int blk  = blockIdx.x;     // 0..799
    const int row0 = blk * 4;        // first row of quad
    const int wave = row0 + wid;     // row id 0..3199

    // Block-uniform sources.
    const __bf16* psrc;
    const char*   bsrc;
    const float*  usrc;
    if (blk < 160) {                 // intra (rows 0..639)
        psrc = vpi + (blk / 40) * (N_ * H1_);
        bsrc = blob_i;
        usrc = ui + row0 * H1_;
    } else {                         // inter (rows 640..3199)
        psrc = vpl + ((blk - 160) / 160) * (N_ * H1_);
        bsrc = blob_l;
        usrc = uq + (row0 - B_ * N_) * H1_;
    }

    // 1) DMA burst: 42 KiB in 1 KiB granules over 4 waves (panel 0..39, u 40..41).
    for (int g = wid; g < 42; g += 4) {
        const char* src = (g < 40) ? (const char*)psrc + (g << 10)
                                   : (const char*)usrc + ((g - 40) << 10);
        __builtin_amdgcn_global_load_lds(
            (const __attribute__((address_space(1))) void*)(src + lane * 16),
            (__attribute__((address_space(3))) void*)(lds + (g << 10)),
            16, 0, 0);
    }

    // 2) W2 fragments + biases straight from global blob (L2-hot, once per
    //    wave; latency overlaps the DMA drain).
    bf16x8 bfr[4][4];
#pragma unroll
    for (int kt = 0; kt < 4; ++kt)
#pragma unroll
        for (int ct = 0; ct < 4; ++ct)
            bfr[kt][ct] = *(const bf16x8*)(bsrc + ((kt * 4 + ct) * 64 + lane) * 16);

    const float* bf32 = (const float*)(bsrc + 16384);
    float b2c[4], w3c[4];
#pragma unroll
    for (int ct = 0; ct < 4; ++ct) {
        b2c[ct] = bf32[16 * ct + c];
        w3c[ct] = bf32[128 + 16 * ct + c];
    }
    const float b3f = bf32[256];

    const int  i     = (wave < B_ * N_ ? wave : wave - B_ * N_) % N_;
    const long obase = (long)wave * N_;   // holds for both branches

    __syncthreads();   // drains DMA (vmcnt) for all waves

    // 3) u halves once from LDS (permuted rows: evens at +0..3, odds +4..7).
    const float* ubase = (const float*)(lds + 40960) + wid * H1_;
    f32x4 ue[4], uo[4];
#pragma unroll
    for (int kt = 0; kt < 4; ++kt) {
        ue[kt] = *(const f32x4*)(ubase + 32 * kt + 8 * q);
        uo[kt] = *(const f32x4*)(ubase + 32 * kt + 8 * q + 4);
    }

    const __bf16* panel = (const __bf16*)lds;

    // 4) Full-row tile loop, software-pipelined: vwb holds jt's 4 panel
    //    fragments; jt+1's reads issue at body top (~300cyc before use).
    u32x4 vwb[4];
    {
        const __bf16* prow0 = panel + c * H1_;
#pragma unroll
        for (int kt = 0; kt < 4; ++kt)
            vwb[kt] = *(const u32x4*)(prow0 + (((4 * kt + q) ^ (c & 7)) << 3));
    }

    for (int jt = 0; jt < 10; ++jt) {
        u32x4 vwn[4];
        if (jt < 9) {
            const __bf16* pnext = panel + (16 * (jt + 1) + c) * H1_;
#pragma unroll
            for (int kt = 0; kt < 4; ++kt)
                vwn[kt] = *(const u32x4*)(pnext + (((4 * kt + q) ^ (c & 7)) << 3));
        }

        f32x4 acc[4];
#pragma unroll
        for (int ct = 0; ct < 4; ++ct)
            acc[ct] = (f32x4){b2c[ct], b2c[ct], b2c[ct], b2c[ct]};

#pragma unroll
        for (int kt = 0; kt < 4; ++kt) {
            const u32x4 vw = vwb[kt];
            bf16x8 av;
#pragma unroll
            for (int d = 0; d < 4; ++d) {
                const unsigned w = vw[d];
                const float lo = __uint_as_float(w << 16) + ue[kt][d];
                const float hi = __uint_as_float(w & 0xffff0000u) + uo[kt][d];
                av[2 * d]     = (__bf16)fmaxf(lo, 0.f);   // pair -> v_cvt_pk_bf16_f32
                av[2 * d + 1] = (__bf16)fmaxf(hi, 0.f);
            }
#pragma unroll
            for (int ct = 0; ct < 4; ++ct)
                acc[ct] = __builtin_amdgcn_mfma_f32_16x16x32_bf16(
                    av, bfr[kt][ct], acc[ct], 0, 0, 0);
        }

        // Epilogue: logit[r] = b3 + sum_col relu(H2pre) * w3 (b2 in acc).
        // 16-lane-group sum via DPP rotation tree (pure VALU, no DS).
        float logit[4];
#pragma unroll
        for (int r = 0; r < 4; ++r) {
            float p = 0.f;
#pragma unroll
            for (int ct = 0; ct < 4; ++ct)
                p += fmaxf(acc[ct][r], 0.f) * w3c[ct];
            DPP_ADD_(p, 0xB1);    // quad_perm [1,0,3,2]  (xor1)
            DPP_ADD_(p, 0x4E);    // quad_perm [2,3,0,1]  (xor2)
            DPP_ADD_(p, 0x124);   // row_ror:4
            DPP_ADD_(p, 0x128);   // row_ror:8
            logit[r] = p;
        }

        if (c < 4) {
            const int j = 16 * jt + 4 * q + c;
            const float lg = logit[c] + b3f;
            const float s = (j == i) ? 0.f : 1.f / (1.f + __expf(-lg));
            out[obase + j] = s;
        }

        if (jt < 9) {
#pragma unroll
            for (int kt = 0; kt < 4; ++kt)
                vwb[kt] = vwn[kt];
        }
    }
}

// ---------------------------------------------------------------------------
extern "C" void kernel_launch(void* const* d_in, const int* in_sizes, int n_in,
                              void* d_out, int out_size, void* d_ws, size_t ws_size,
                              hipStream_t stream) {
    const float* ne  = (const float*)d_in[0];
    const float* zi  = (const float*)d_in[1];
    const float* ze  = (const float*)d_in[2];
    const float* lag = (const float*)d_in[3];
    const float* Wi1 = (const float*)d_in[4];
    const float* bi1 = (const float*)d_in[5];
    const float* Wi2 = (const float*)d_in[6];
    const float* bi2 = (const float*)d_in[7];
    const float* Wi3 = (const float*)d_in[8];
    const float* bi3 = (const float*)d_in[9];
    const float* Wl1 = (const float*)d_in[10];
    const float* bl1 = (const float*)d_in[11];
    const float* Wl2 = (const float*)d_in[12];
    const float* bl2 = (const float*)d_in[13];
    const float* Wl3 = (const float*)d_in[14];
    const float* bl3 = (const float*)d_in[15];

    float*  ws     = (float*)d_ws;
    float*  ui     = ws;                        // 640*128 fp32 (permuted rows)
    float*  uqw    = ws + 81920;                // 2560*128 fp32 (permuted rows)
    __bf16* vpi    = (__bf16*)(ws + 409600);    // 640*128 bf16 (pre-swizzled)
    __bf16* vpl    = vpi + 81920;               // 640*128 bf16 (pre-swizzled)
    char*   blob_i = (char*)d_ws + 1966080;     // 20480 B setup blob (intra)
    char*   blob_l = blob_i + 20480;            // 20480 B setup blob (inter)

    stage_a<<<B_ * N_, 128, 0, stream>>>(ne, zi, ze, lag, Wi1, bi1, Wl1, bl1,
                                         Wi2, bi2, Wi3, bi3, Wl2, bl2, Wl3, bl3,
                                         ui, uqw, vpi, vpl, blob_i, blob_l);

    stage_b<<<800, 256, 0, stream>>>(
        ui, uqw, vpi, vpl, blob_i, blob_l,
        (float*)d_out);
}